// Round 12
// baseline (3662.512 us; speedup 1.0000x reference)
//
#include <hip/hip_runtime.h>
#include <hip/hip_bf16.h>

// Problem constants
#define B_    128
#define T_    512
#define IN_   128
#define H_    1024
#define OUT_  64
#define KTOT  1152          // IN_ + H_
#define GB    8             // row groups (16 rows each) == independent chains
#define GH    32            // col groups (32 units = 128 gate-cols each)
// Blocked Hall layout: [t][uq(256 unit-quads)][rg(8)][16 rows][4 cols] ushort.
// element (b,u) -> (u>>2)*512 + (b>>4)*64 + (b&15)*4 + (u&3).
// t-slab = 131072 ushorts (256KB). Each producer wave's 16x4 tile is 128B
// contiguous & aligned -> line-clean single-writer publish (r11, verified).
#define HSLAB 131072

typedef short bf16x8 __attribute__((ext_vector_type(8)));
typedef short s16x4  __attribute__((ext_vector_type(4)));
typedef float f32x4  __attribute__((ext_vector_type(4)));

#define MFMA(a,b,c) __builtin_amdgcn_mfma_f32_16x16x32_bf16((a),(b),(c),0,0,0)

__device__ __forceinline__ unsigned short f2bf(float x) {
    unsigned int xi = __float_as_uint(x);
    unsigned int r  = (xi + 0x7fffu + ((xi >> 16) & 1u)) >> 16;
    return (unsigned short)r;
}

// ---------------------------------------------------------------------------
// Pack combined recurrent weights: Wp[c][k] bf16; gate-col c: unit c>>2,
// gate c&3 (0,1,2 = f,i,z from kernel_fiz col gate*H + unit; 3 = r).
// ---------------------------------------------------------------------------
__global__ void pack_weights(const float* __restrict__ kfiz, const float* __restrict__ kr,
                             const float* __restrict__ bfiz, const float* __restrict__ br,
                             unsigned short* __restrict__ Wp, float* __restrict__ biasp)
{
    const int c    = blockIdx.x;            // 0..4095
    const int j    = c >> 2;
    const int gate = c & 3;
    for (int k = threadIdx.x; k < KTOT; k += 256) {
        float v = (gate < 3) ? kfiz[(size_t)k * 3072 + gate * 1024 + j]
                             : kr[(size_t)k * 1024 + j];
        Wp[(size_t)c * KTOT + k] = f2bf(v);
    }
    if (threadIdx.x == 0)
        biasp[c] = (gate < 3) ? bfiz[gate * 1024 + j] : br[j];
}

// u (B,T,IN) fp32 -> Ubf (T,B,IN) bf16
__global__ void pack_u(const float* __restrict__ u, unsigned short* __restrict__ Ubf)
{
    size_t i = (size_t)blockIdx.x * 256 + threadIdx.x;   // < 8388608
    int t = (int)(i >> 14);
    int rem = (int)(i & 16383);
    int b = rem >> 7, k = rem & 127;
    Ubf[i] = f2bf(u[((size_t)b << 16) + ((size_t)t << 7) + k]);
}

// W_out (H,OUT) fp32 -> Wob[o][k] bf16
__global__ void pack_wout(const float* __restrict__ wo, unsigned short* __restrict__ Wob)
{
    const int o = blockIdx.x;               // 0..63
    for (int k = threadIdx.x; k < H_; k += 256)
        Wob[(size_t)o * H_ + k] = f2bf(wo[(size_t)k * OUT_ + o]);
}

// ---------------------------------------------------------------------------
// Persistent recurrent scan — ROW-PARTITIONED, BARRIER-FREE WAVES.
// WG (rg = bid&7, cg = bid>>3): rows rg*16..+16, units cg*32..+32. Each wave
// owns ONE 16x16 output tile with FULL K=1152 (36 MFMAs): no partial
// exchange, no intra-step __syncthreads. All 8 waves read the same 16-row
// A-panel (L1-amortized). 8 independent row-chains of 32 WGs each (LSTM
// recurrence is per-batch-row); rg = bid&7 puts a chain on one XCD under
// round-robin dispatch (locality bonus only — protocol is mapping-agnostic).
// Protocol (proven r4 class): producers publish line-clean 128B tiles
// (agent stores), drain own stores, post done[wave] in LDS; wave0 aggregates
// + sets per-WG flag (flag => globally visible). Consumers: wave0-only tight
// 32-flag poll (one poller per WG — r6 law), LDS rel fan-out (r10 mechanism,
// minimal body), then PLAIN cached bulk loads (r2/r5 law). All spins bounded:
// any protocol failure is a visible absmax failure, never a hang.
// ---------------------------------------------------------------------------
__global__ void __launch_bounds__(512, 2)
lstm_scan(const float* __restrict__ x0,
          const unsigned short* __restrict__ Wp,
          const float* __restrict__ biasp,
          const unsigned short* __restrict__ Ubf,
          unsigned short* __restrict__ Hall,
          int* __restrict__ Flag)
{
    __shared__ int rel;                       // consumer release counter
    __shared__ int done[8];                   // per-wave publish-drained counters

    const int tid  = threadIdx.x;
    const int bid  = blockIdx.x;
    const int rg   = bid & 7;                 // row group / chain (16 rows)
    const int cg   = bid >> 3;                // col group (32 units)
    const int wave = tid >> 6;
    const int lane = tid & 63;
    const int quad = lane >> 4;
    const int l15  = lane & 15;
    const int g    = l15 & 3;                 // gate id of this lane's column
    const int rb   = rg * 16;                 // row base

    const int c = cg * 128 + wave * 16 + l15; // this lane's gate-col (0..4095)

    // Weights: full K for this lane's col; 36 chunks x 8 bf16 (B-frag layout).
    f32x4 wregf[36];
    #pragma unroll
    for (int kk = 0; kk < 36; ++kk)
        wregf[kk] = *reinterpret_cast<const f32x4*>(
            Wp + (size_t)c * KTOT + kk * 32 + quad * 8);
    #pragma unroll
    for (int i = 0; i < 36; ++i)
        asm volatile("" : "+v"(wregf[i]));    // pin: no remat, keep in VGPRs

    const float bias = biasp[c];
    const int j = c >> 2;                     // unit of this lane's col

    // c-state (fp32): rows rb+quad*4+r, unit j (C/D layout: col=l15, row=quad*4+reg)
    float cst[4];
    #pragma unroll
    for (int r = 0; r < 4; ++r)
        cst[r] = x0[(size_t)(rb + quad * 4 + r) * 2048 + 1024 + j];

    if (tid == 0) rel = 0;
    if (tid < 8) done[tid] = 0;

    // h0 -> Hall[0]: WG's 16 rows x 32 units (512 elems, 512 threads)
    {
        int m = tid >> 5, uu = tid & 31;
        int uq = cg * 8 + (uu >> 2);
        unsigned short hv = f2bf(x0[(size_t)(rb + m) * 2048 + cg * 32 + uu]);
        __hip_atomic_store(&Hall[(size_t)uq * 512 + rg * 64 + m * 4 + (uu & 3)], hv,
                           __ATOMIC_RELAXED, __HIP_MEMORY_SCOPE_AGENT);
    }
    __syncthreads();                           // one-time: drain + rel/done init
    if (tid == 0)
        __hip_atomic_store(&Flag[(size_t)rg * 32 + cg], 1,
                           __ATOMIC_RELAXED, __HIP_MEMORY_SCOPE_AGENT);

    // A-operand bases. A-frag: row = l15, k = quad*8 + e.
    const unsigned short* aU = Ubf + (size_t)(rb + l15) * IN_ + quad * 8;
    // h chunk kk: uq0 = (kk-4)*8 + quad*2; two 8B runs at +0 and +512 ushorts.
    const unsigned short* aH = Hall + (size_t)quad * 1024 + rg * 64 + l15 * 4;
    // Publish: wave tile uq = cg*8+wave, row quad*4+(l15>>2) (after transpose).
    const size_t pubAdr = (size_t)(cg * 8 + wave) * 512 + rg * 64
                        + (size_t)(quad * 4 + (l15 >> 2)) * 4;

    for (int t = 0; t < T_; ++t) {
        f32x4 acc[4] = {{0.f,0.f,0.f,0.f},{0.f,0.f,0.f,0.f},
                        {0.f,0.f,0.f,0.f},{0.f,0.f,0.f,0.f}};

        // ---- u-part: chunks 0..3 (independent of h[t], pre-release) ----
        {
            const unsigned short* au = aU + (size_t)t * (B_ * IN_);
            #pragma unroll
            for (int kk = 0; kk < 4; ++kk) {
                bf16x8 av = *reinterpret_cast<const bf16x8*>(au + kk * 32);
                acc[kk] = MFMA(av, __builtin_bit_cast(bf16x8, wregf[kk]), acc[kk]);
            }
        }

        // ---- release: wave0 tight-polls this chain's 32 flags; LDS fan-out ----
        if (wave == 0) {
            const int* fp = Flag + ((size_t)t * 8 + rg) * 32 + (lane & 31);
            int v = __hip_atomic_load(fp, __ATOMIC_RELAXED, __HIP_MEMORY_SCOPE_AGENT);
            for (int gd = 0; gd < (1 << 20) && !__all(v != 0); ++gd)
                v = __hip_atomic_load(fp, __ATOMIC_RELAXED, __HIP_MEMORY_SCOPE_AGENT);
            if (lane == 0)
                __hip_atomic_store(&rel, t + 1, __ATOMIC_RELEASE, __HIP_MEMORY_SCOPE_WORKGROUP);
        } else {
            for (int gd = 0; gd < (1 << 20); ++gd)
                if (__hip_atomic_load(&rel, __ATOMIC_ACQUIRE, __HIP_MEMORY_SCOPE_WORKGROUP) >= t + 1)
                    break;
        }
        asm volatile("" ::: "memory");         // no h-load hoists above release

        // ---- h-part: chunks 4..35, plain cached loads (L1/L2-amortized) ----
        const unsigned short* ah = aH + (size_t)t * HSLAB;
        #pragma unroll
        for (int grp = 0; grp < 8; ++grp) {
            union AV { s16x4 h[2]; bf16x8 v; } ab[4];
            #pragma unroll
            for (int i = 0; i < 4; ++i) {
                const unsigned short* p = ah + (size_t)(grp * 4 + i) * 4096;
                ab[i].h[0] = *reinterpret_cast<const s16x4*>(p);
                ab[i].h[1] = *reinterpret_cast<const s16x4*>(p + 512);
            }
            #pragma unroll
            for (int i = 0; i < 4; ++i) {
                const int kk = 4 + grp * 4 + i;
                acc[kk & 3] = MFMA(ab[i].v, __builtin_bit_cast(bf16x8, wregf[kk]), acc[kk & 3]);
            }
        }

        // ---- combine partial accumulators (no LDS exchange needed) ----
        f32x4 s = (acc[0] + acc[1]) + (acc[2] + acc[3]);

        // ---- epilogue: activations, cross-gate exchange, state update ----
        unsigned int hx = 0, hy = 0;           // 4 packed bf16 hn (rows r=0..3)
        #pragma unroll
        for (int r = 0; r < 4; ++r) {
            float pre = s[r] + bias;
            float sg  = 1.0f / (1.0f + __expf((g == 3) ? -2.0f * pre : -pre));
            float act = (g == 3) ? 2.0f * sg - 1.0f : sg;
            float x1 = __shfl_xor(act, 1);
            float x2 = __shfl_xor(act, 2);
            float x3 = __shfl_xor(x1, 2);
            float fv = (g == 0) ? act : (g == 1) ? x1 : (g == 2) ? x2 : x3;
            int gi = g ^ 1;
            float iv = (gi == 0) ? act : (gi == 1) ? x1 : (gi == 2) ? x2 : x3;
            int gz = g ^ 2;
            float zv = (gz == 0) ? act : (gz == 1) ? x1 : (gz == 2) ? x2 : x3;
            int gr = g ^ 3;
            float rv = (gr == 0) ? act : (gr == 1) ? x1 : (gr == 2) ? x2 : x3;

            float cn = fv * cst[r] + iv * rv;
            cst[r] = cn;
            float th = 2.0f / (1.0f + __expf(-2.0f * cn)) - 1.0f;
            float hn = zv * th;
            unsigned int hb = f2bf(hn);
            if (r == 0)      hx  = hb;
            else if (r == 1) hx |= hb << 16;
            else if (r == 2) hy  = hb;
            else             hy |= hb << 16;
        }

        // ---- in-register 4x4 transpose among same-gate lanes (r11, proven) ----
        unsigned int px = __shfl_xor((int)hx, 4), py = __shfl_xor((int)hy, 4);
        unsigned int ax, ay;
        if ((lane & 4) == 0) { ax = (hx & 0xFFFFu) | (px << 16);
                               ay = (hy & 0xFFFFu) | (py << 16); }
        else                 { ax = (px >> 16) | (hx & 0xFFFF0000u);
                               ay = (py >> 16) | (hy & 0xFFFF0000u); }
        unsigned int qx = __shfl_xor((int)ax, 8), qy = __shfl_xor((int)ay, 8);
        unsigned int bx, by;
        if ((lane & 8) == 0) { bx = ax; by = qx; }
        else                 { bx = qy; by = ay; }

        // ---- line-clean publish: this wave's 128B contiguous tile ----
        if (g == 0) {
            unsigned long long val = ((unsigned long long)by << 32) | bx;
            __hip_atomic_store(
                (unsigned long long*)&Hall[(size_t)(t + 1) * HSLAB + pubAdr], val,
                __ATOMIC_RELAXED, __HIP_MEMORY_SCOPE_AGENT);
        }
        asm volatile("s_waitcnt vmcnt(0)" ::: "memory");   // drain OWN stores only

        if (wave == 0) {
            // own tile drained; wait for the other 7 waves' done (LDS, cheap)
            const int dv = t + 1;
            for (int gd = 0; gd < (1 << 20); ++gd) {
                int v = (lane >= 1 && lane < 8)
                      ? __hip_atomic_load(&done[lane], __ATOMIC_ACQUIRE, __HIP_MEMORY_SCOPE_WORKGROUP)
                      : dv;
                if (__all(v >= dv)) break;
            }
            asm volatile("" ::: "memory");
            if (lane == 0)
                __hip_atomic_store(&Flag[((size_t)(t + 1) * 8 + rg) * 32 + cg], 1,
                                   __ATOMIC_RELAXED, __HIP_MEMORY_SCOPE_AGENT);
        } else {
            if (lane == 0)
                __hip_atomic_store(&done[wave], t + 1,
                                   __ATOMIC_RELEASE, __HIP_MEMORY_SCOPE_WORKGROUP);
            // run ahead into step t+1 (u-part + rel spin) — no barrier.
        }
    }
}

// ---------------------------------------------------------------------------
// y[b][t][o] = Hall[t+1][.] @ Wob[o][:] + bout[o]   (uq-blocked Hall)
// ---------------------------------------------------------------------------
__global__ void __launch_bounds__(256, 2)
out_gemm(const unsigned short* __restrict__ Hall,
         const unsigned short* __restrict__ Wob,
         const float* __restrict__ bout,
         float* __restrict__ y)
{
    const int tid  = threadIdx.x, wave = tid >> 6, lane = tid & 63;
    const int quad = lane >> 4, l15 = lane & 15;
    const int R    = blockIdx.x * 64 + wave * 16;      // flat row t*128+b

    f32x4 acc[4];
    #pragma unroll
    for (int nt = 0; nt < 4; ++nt) {
        float bb = bout[nt * 16 + l15];
        acc[nt] = {bb, bb, bb, bb};
    }
    const int fr = R + l15;                    // flat row; same t across the wave
    const int b  = fr & 127;
    const unsigned short* ap = Hall + ((size_t)(fr >> 7) + 1) * HSLAB
                             + (size_t)quad * 1024 + (b >> 4) * 64 + (b & 15) * 4;
    #pragma unroll 4
    for (int kk = 0; kk < 32; ++kk) {          // chunk kk: uq0 = kk*8 + quad*2
        union { s16x4 h[2]; bf16x8 v; } uu;
        uu.h[0] = *reinterpret_cast<const s16x4*>(ap + (size_t)kk * 4096);
        uu.h[1] = *reinterpret_cast<const s16x4*>(ap + (size_t)kk * 4096 + 512);
        bf16x8 av = uu.v;
        #pragma unroll
        for (int nt = 0; nt < 4; ++nt) {
            bf16x8 bv = *reinterpret_cast<const bf16x8*>(
                Wob + (size_t)(nt * 16 + l15) * H_ + kk * 32 + quad * 8);
            acc[nt] = MFMA(av, bv, acc[nt]);
        }
    }
    #pragma unroll
    for (int nt = 0; nt < 4; ++nt)
        #pragma unroll
        for (int r = 0; r < 4; ++r) {
            int row = R + quad * 4 + r;
            int bb2 = row & 127, t = row >> 7;
            y[((size_t)bb2 << 15) + ((size_t)t << 6) + nt * 16 + l15] = acc[nt][r];
        }
}

// ---------------------------------------------------------------------------
extern "C" void kernel_launch(void* const* d_in, const int* in_sizes, int n_in,
                              void* d_out, int out_size, void* d_ws, size_t ws_size,
                              hipStream_t stream)
{
    const float* u    = (const float*)d_in[0];
    const float* x0   = (const float*)d_in[1];
    const float* kfiz = (const float*)d_in[2];
    const float* bfiz = (const float*)d_in[3];
    const float* kr   = (const float*)d_in[4];
    const float* br   = (const float*)d_in[5];
    const float* wo   = (const float*)d_in[6];
    const float* bo   = (const float*)d_in[7];
    float* y = (float*)d_out;

    char* ws = (char*)d_ws;
    size_t off = 0;
    unsigned short* Wp    = (unsigned short*)(ws + off); off += (size_t)4096 * KTOT * 2;        // 9,437,184
    float*          biasp = (float*)(ws + off);          off += (size_t)4096 * 4;               // 16,384
    unsigned short* Wob   = (unsigned short*)(ws + off); off += (size_t)OUT_ * H_ * 2;          // 131,072
    unsigned short* Ubf   = (unsigned short*)(ws + off); off += (size_t)T_ * B_ * IN_ * 2;      // 16,777,216
    unsigned short* Hall  = (unsigned short*)(ws + off); off += (size_t)(T_ + 1) * B_ * H_ * 2; // 134,479,872
    int*            Flag  = (int*)(ws + off);            off += (size_t)(T_ + 1) * GB * GH * 4; // 525,312
    if (off > ws_size) return;   // workspace too small: deterministic visible failure

    hipMemsetAsync(Flag, 0, (size_t)(T_ + 1) * GB * GH * 4, stream);
    hipLaunchKernelGGL(pack_weights, dim3(4096),  dim3(256), 0, stream, kfiz, kr, bfiz, br, Wp, biasp);
    hipLaunchKernelGGL(pack_u,       dim3(32768), dim3(256), 0, stream, u, Ubf);
    hipLaunchKernelGGL(pack_wout,    dim3(64),    dim3(256), 0, stream, wo, Wob);

    void* args[] = { (void*)&x0, (void*)&Wp, (void*)&biasp, (void*)&Ubf, (void*)&Hall, (void*)&Flag };
    hipLaunchCooperativeKernel((void*)lstm_scan, dim3(GB * GH), dim3(512), args, 0, stream);

    hipLaunchKernelGGL(out_gemm, dim3((T_ * B_) / 64), dim3(256), 0, stream, Hall, Wob, bo, y);
}